// Round 8
// baseline (198.285 us; speedup 1.0000x reference)
//
#include <hip/hip_runtime.h>
#include <stdint.h>

#define DI __device__ __forceinline__

typedef __attribute__((ext_vector_type(8))) __bf16 bf16x8;
typedef __attribute__((ext_vector_type(8))) unsigned short u16x8;
typedef __attribute__((ext_vector_type(4))) float f32x4;
typedef __attribute__((ext_vector_type(4))) uint32_t u32x4;
typedef __attribute__((ext_vector_type(4))) unsigned short u16x4;
typedef unsigned short u16;

constexpr int Bb = 4, Cc = 256, Ss = 4096, HD = 64;
constexpr int ELEMS = Bb * Cc * Ss;  // 4194304

DI u16 f2bf(float f) {
  union { float f; unsigned u; } x; x.f = f;
  return (u16)((x.u + 0x7FFFu + ((x.u >> 16) & 1u)) >> 16);
}
DI uint32_t pack2bf(float a, float b) {  // low16=bf(a), high16=bf(b)
  union { float f; uint32_t u; } xa, xb;
  xa.f = a; xb.f = b;
  return __builtin_amdgcn_perm(xb.u + 0x8000u, xa.u + 0x8000u, 0x07060302u);
}
DI bf16x8 ldfrag(const u16* p) { return __builtin_bit_cast(bf16x8, *(const u16x8*)p); }

// ---------------- fp32 -> bf16 convert, both weight matrices in one launch ----------------
__global__ __launch_bounds__(256) void k_convw(const float* __restrict__ w1, const float* __restrict__ w2,
                                               u16* __restrict__ d1, u16* __restrict__ d2) {
  int i = blockIdx.x * 256 + threadIdx.x;
  if (i < 196608) d1[i] = f2bf(w1[i]);
  if (i < 65536) d2[i] = f2bf(w2[i]);
}

// ---------------- kernel 0: x (B,C,S) fp32 -> xt (B,S,C) bf16 ----------------
__global__ __launch_bounds__(256) void k_transpose(const float* __restrict__ x, u16* __restrict__ xt) {
  __shared__ u16 T[64][72];
  const int st = blockIdx.x, ct = blockIdx.y, b = blockIdx.z;
  const int tid = threadIdx.x;
#pragma unroll
  for (int e = 0; e < 2; e++) {
    int ss = tid + e * 256;
    int r = ss >> 3, seg = ss & 7;
    size_t base = ((size_t)(b * Cc + ct * 64 + r) << 12) + st * 64 + seg * 8;
    u16x8 t;
#pragma unroll
    for (int j = 0; j < 8; j++) t[j] = f2bf(x[base + j]);
    *(u16x8*)&T[r][seg * 8] = t;
  }
  __syncthreads();
#pragma unroll
  for (int e = 0; e < 2; e++) {
    int ss = tid + e * 256;
    int sr = ss >> 3, cseg = ss & 7;
    u16x8 o;
#pragma unroll
    for (int j = 0; j < 8; j++) o[j] = T[cseg * 8 + j][sr];
    *(u16x8*)(xt + ((size_t)(b * Ss + st * 64 + sr) << 8) + ct * 64 + cseg * 8) = o;
  }
}

// ---- shared GEMM staging: rows [r0,r0+128) x cols [k0,k0+32), pitch-40 LDS ----
DI void stage_tile(const u16* __restrict__ src, int pitch, int r0, int k0, u16 (*dst)[40], int tid) {
#pragma unroll
  for (int e = 0; e < 2; e++) {
    int c = tid + e * 256;
    int row = c >> 2, seg = c & 3;
    u16x8 t = *(const u16x8*)(src + (size_t)(r0 + row) * pitch + k0 + seg * 8);
    *(u16x8*)&dst[row][seg * 8] = t;
  }
}

// ---------------- kernel 1: qkv GEMM.  q:[bh][s][64]*(0.125*log2e)  k,v:[bh][s][64] ----------------
__global__ __launch_bounds__(256) void k_qkv(const u16* __restrict__ xt, const u16* __restrict__ w,
                                             const float* __restrict__ bias,
                                             u16* __restrict__ q, u16* __restrict__ kk_, u16* __restrict__ vv_) {
  __shared__ u16 As[128][40], Bs[128][40];
  const int tid = threadIdx.x;
  const int wv = tid >> 6, lane = tid & 63;
  const int wm = wv >> 1, wn = wv & 1;
  const int lr = lane & 15, quad = lane >> 4;
  const int r0 = blockIdx.x * 128;
  const int j0 = blockIdx.y * 128;
  f32x4 acc[4][4] = {};
  for (int k0 = 0; k0 < 256; k0 += 32) {
    __syncthreads();
    stage_tile(xt, 256, r0, k0, As, tid);
    stage_tile(w, 256, j0, k0, Bs, tid);
    __syncthreads();
    bf16x8 a[4], b[4];
#pragma unroll
    for (int mt = 0; mt < 4; mt++) a[mt] = ldfrag(&As[wm * 64 + mt * 16 + lr][quad * 8]);
#pragma unroll
    for (int nt = 0; nt < 4; nt++) b[nt] = ldfrag(&Bs[wn * 64 + nt * 16 + lr][quad * 8]);
#pragma unroll
    for (int mt = 0; mt < 4; mt++)
#pragma unroll
      for (int nt = 0; nt < 4; nt++)
        acc[mt][nt] = __builtin_amdgcn_mfma_f32_16x16x32_bf16(a[mt], b[nt], acc[mt][nt], 0, 0, 0);
  }
#pragma unroll
  for (int nt = 0; nt < 4; nt++) {
    int j = j0 + wn * 64 + nt * 16 + lr;
    float bj = bias[j];
    int part = j >> 8, cc = j & 255, head = cc >> 6, d = cc & 63;
    u16* outp = (part == 0) ? q : (part == 1) ? kk_ : vv_;
    float sc = (part == 0) ? 0.18033688f : 1.0f;  // 0.125*log2(e), exp2-domain scores
#pragma unroll
    for (int mt = 0; mt < 4; mt++)
#pragma unroll
      for (int rg = 0; rg < 4; rg++) {
        int row = r0 + wm * 64 + mt * 16 + quad * 4 + rg;
        int b_ = row >> 12, s = row & 4095;
        outp[((size_t)((b_ * 4 + head) * Ss + s) << 6) + d] = f2bf((acc[mt][nt][rg] + bj) * sc);
      }
  }
}

// ---------------- v [bh][s][64] -> vt [bh][d][chunk*64 + slot] (key-permuted transpose) ----------------
__global__ __launch_bounds__(256) void k_vt(const u16* __restrict__ v, u16* __restrict__ vt) {
  __shared__ u16 T[64][72];
  const int chunk = blockIdx.x, bh = blockIdx.y;
  const int tid = threadIdx.x;
#pragma unroll
  for (int e = 0; e < 2; e++) {
    int row = (tid >> 3) + e * 32, seg = tid & 7;
    *(u16x8*)&T[row][seg * 8] =
        *(const u16x8*)(v + ((size_t)(bh * Ss + chunk * 64 + row) << 6) + seg * 8);
  }
  __syncthreads();
#pragma unroll
  for (int e = 0; e < 2; e++) {
    int d = (tid >> 3) + e * 32, seg = tid & 7;
    u16x8 o;
#pragma unroll
    for (int j = 0; j < 8; j++) {
      int slot = seg * 8 + j;
      // inverse of slot = ((t>>1)<<5)|(qq<<3)|((t&1)<<2)|r
      int t = (((slot >> 5) & 1) << 1) | ((slot >> 2) & 1);
      int w6 = t * 16 + (((slot >> 3) & 3) << 2) + (slot & 3);
      o[j] = T[w6][d];
    }
    *(u16x8*)(vt + ((size_t)(bh * 64 + d) << 12) + chunk * 64 + seg * 8) = o;
  }
}

// ---------------- kernel 2: flash attention, S^T form, exp2 no-max softmax ----------------
// 64 queries/wave, 256 q-rows/block (4 waves), double-buffered K/V staging, 1 barrier/chunk,
// K-split over blockIdx.z (linear softmax => partials add exactly).
__global__ __launch_bounds__(256, 2) void k_attn(const u16* __restrict__ Q, const u16* __restrict__ K,
                                                 const u16* __restrict__ VT, u16* __restrict__ AO,
                                                 float* __restrict__ Opart, float* __restrict__ lpart,
                                                 int nsplit) {
  __shared__ u16 Kl[2][64][72];
  __shared__ u16 Vl[2][64][72];
  const int tid = threadIdx.x;
  const int wv = tid >> 6, lane = tid & 63;
  const int lr = lane & 15, quad = lane >> 4;
  const int bh = blockIdx.y;
  const int b_ = bh >> 2, head = bh & 3;
  const int qbase = blockIdx.x * 256 + wv * 64;
  const int sp = blockIdx.z;
  const int nchunk = 64 / nsplit, kcg0 = sp * nchunk;
  const u16* Qh = Q + (size_t)bh * Ss * HD;
  const u16* Kh = K + (size_t)bh * Ss * HD;
  const u16* Vh = VT + (size_t)bh * HD * Ss;  // [d][perm(s)]

  bf16x8 qb[4][2];
#pragma unroll
  for (int nt = 0; nt < 4; nt++)
#pragma unroll
    for (int ks = 0; ks < 2; ks++)
      qb[nt][ks] = ldfrag(Qh + (size_t)(qbase + nt * 16 + lr) * HD + ks * 32 + quad * 8);

  f32x4 O[4][4] = {};
  float lsum[4] = {0.f, 0.f, 0.f, 0.f};

  u16x8 pf[4];
  const int srow = tid >> 3, sseg = tid & 7;
  auto load_chunk = [&](int kc) {
#pragma unroll
    for (int e = 0; e < 2; e++) {
      pf[e] = *(const u16x8*)(Kh + ((size_t)((kcg0 + kc) * 64 + srow + e * 32) << 6) + sseg * 8);
      pf[2 + e] = *(const u16x8*)(Vh + ((size_t)(srow + e * 32) << 12) + (kcg0 + kc) * 64 + sseg * 8);
    }
  };
  auto store_chunk = [&](int buf) {
#pragma unroll
    for (int e = 0; e < 2; e++) {
      *(u16x8*)&Kl[buf][srow + e * 32][sseg * 8] = pf[e];
      *(u16x8*)&Vl[buf][srow + e * 32][sseg * 8] = pf[2 + e];
    }
  };

  load_chunk(0);
  store_chunk(0);
  if (nchunk > 1) load_chunk(1);
  __syncthreads();

  for (int kc = 0; kc < nchunk; kc++) {
    const int cur = kc & 1;
    f32x4 St[4][4] = {};
#pragma unroll
    for (int ks = 0; ks < 2; ks++) {
      bf16x8 ka[4];
#pragma unroll
      for (int kt = 0; kt < 4; kt++) ka[kt] = ldfrag(&Kl[cur][kt * 16 + lr][ks * 32 + quad * 8]);
#pragma unroll
      for (int kt = 0; kt < 4; kt++)
#pragma unroll
        for (int nt = 0; nt < 4; nt++)
          St[kt][nt] = __builtin_amdgcn_mfma_f32_16x16x32_bf16(ka[kt], qb[nt][ks], St[kt][nt], 0, 0, 0);
    }

    uint32_t pk[4][4][2];
#pragma unroll
    for (int kt = 0; kt < 4; kt++)
#pragma unroll
      for (int nt = 0; nt < 4; nt++) {
        float p0 = __builtin_amdgcn_exp2f(St[kt][nt][0]);
        float p1 = __builtin_amdgcn_exp2f(St[kt][nt][1]);
        float p2 = __builtin_amdgcn_exp2f(St[kt][nt][2]);
        float p3 = __builtin_amdgcn_exp2f(St[kt][nt][3]);
        lsum[nt] += (p0 + p1) + (p2 + p3);
        pk[kt][nt][0] = pack2bf(p0, p1);
        pk[kt][nt][1] = pack2bf(p2, p3);
      }

#pragma unroll
    for (int ks = 0; ks < 2; ks++) {
      bf16x8 pa[4];
#pragma unroll
      for (int mt = 0; mt < 4; mt++) {
        u32x4 t = {pk[2 * ks][mt][0], pk[2 * ks][mt][1], pk[2 * ks + 1][mt][0], pk[2 * ks + 1][mt][1]};
        pa[mt] = __builtin_bit_cast(bf16x8, t);
      }
#pragma unroll
      for (int dt = 0; dt < 4; dt++) {
        bf16x8 vb = ldfrag(&Vl[cur][dt * 16 + lr][ks * 32 + quad * 8]);
#pragma unroll
        for (int mt = 0; mt < 4; mt++)
          O[mt][dt] = __builtin_amdgcn_mfma_f32_16x16x32_bf16(pa[mt], vb, O[mt][dt], 0, 0, 0);
      }
    }

    if (kc + 1 < nchunk) {
      store_chunk(cur ^ 1);
      if (kc + 2 < nchunk) load_chunk(kc + 2);
    }
    __syncthreads();
  }

#pragma unroll
  for (int nt = 0; nt < 4; nt++) {
    lsum[nt] += __shfl_xor(lsum[nt], 16);
    lsum[nt] += __shfl_xor(lsum[nt], 32);
  }

  if (nsplit == 1) {
#pragma unroll
    for (int mt = 0; mt < 4; mt++)
#pragma unroll
      for (int rg = 0; rg < 4; rg++) {
        float lv = __shfl(lsum[mt], quad * 4 + rg);
        float inv = 1.0f / lv;
        int s = qbase + mt * 16 + quad * 4 + rg;
#pragma unroll
        for (int dt = 0; dt < 4; dt++)
          AO[((size_t)(b_ * Ss + s) << 8) + head * 64 + dt * 16 + lr] = f2bf(O[mt][dt][rg] * inv);
      }
  } else {
    float* Op = Opart + (size_t)sp * ELEMS;
    float* lp = lpart + (size_t)sp * (16 * Ss) + bh * Ss;
    if (quad == 0) {
#pragma unroll
      for (int nt = 0; nt < 4; nt++) lp[qbase + nt * 16 + lr] = lsum[nt];
    }
#pragma unroll
    for (int mt = 0; mt < 4; mt++)
#pragma unroll
      for (int rg = 0; rg < 4; rg++) {
        int s = qbase + mt * 16 + quad * 4 + rg;
#pragma unroll
        for (int dt = 0; dt < 4; dt++)
          Op[((size_t)(b_ * Ss + s) << 8) + head * 64 + dt * 16 + lr] = O[mt][dt][rg];
      }
  }
}

// ---------------- combine split partials: ao = (sum O_i)/(sum l_i), bf16 ----------------
__global__ __launch_bounds__(256) void k_comb(const float* __restrict__ Opart, const float* __restrict__ lpart,
                                              u16* __restrict__ ao, int nsplit) {
  int idx = (blockIdx.x * 256 + threadIdx.x) * 4;
  int c = idx & 255, bs = idx >> 8;
  int b = bs >> 12, s = bs & 4095, head = c >> 6;
  int li = (b * 4 + head) * Ss + s;
  f32x4 oacc = *(const f32x4*)(Opart + idx);
  float l = lpart[li];
  for (int j = 1; j < nsplit; j++) {
    f32x4 oj = *(const f32x4*)(Opart + (size_t)j * ELEMS + idx);
#pragma unroll
    for (int t = 0; t < 4; t++) oacc[t] += oj[t];
    l += lpart[(size_t)j * 16 * Ss + li];
  }
  float inv = 1.0f / l;
  u16x4 o;
#pragma unroll
  for (int j = 0; j < 4; j++) o[j] = f2bf(oacc[j] * inv);
  *(u16x4*)(ao + idx) = o;
}

// ---------------- kernel 3: y^T = w_o * ao^T + b_o, stored as y[b][c][s] FP32 ----------------
__global__ __launch_bounds__(256) void k_oproj(const u16* __restrict__ wo, const u16* __restrict__ ao,
                                               const float* __restrict__ bo, float* __restrict__ y) {
  __shared__ u16 As[128][40], Bs[128][40];
  const int tid = threadIdx.x;
  const int wv = tid >> 6, lane = tid & 63;
  const int wm = wv >> 1, wn = wv & 1;
  const int lr = lane & 15, quad = lane >> 4;
  const int c0 = blockIdx.x * 128;
  const int n0 = blockIdx.y * 128;
  f32x4 acc[4][4] = {};
  for (int k0 = 0; k0 < 256; k0 += 32) {
    __syncthreads();
    stage_tile(wo, 256, c0, k0, As, tid);
    stage_tile(ao, 256, n0, k0, Bs, tid);
    __syncthreads();
    bf16x8 a[4], b[4];
#pragma unroll
    for (int mt = 0; mt < 4; mt++) a[mt] = ldfrag(&As[wm * 64 + mt * 16 + lr][quad * 8]);
#pragma unroll
    for (int nt = 0; nt < 4; nt++) b[nt] = ldfrag(&Bs[wn * 64 + nt * 16 + lr][quad * 8]);
#pragma unroll
    for (int mt = 0; mt < 4; mt++)
#pragma unroll
      for (int nt = 0; nt < 4; nt++)
        acc[mt][nt] = __builtin_amdgcn_mfma_f32_16x16x32_bf16(a[mt], b[nt], acc[mt][nt], 0, 0, 0);
  }
#pragma unroll
  for (int mt = 0; mt < 4; mt++)
#pragma unroll
    for (int rg = 0; rg < 4; rg++) {
      int c = c0 + wm * 64 + mt * 16 + quad * 4 + rg;
      float bc = bo[c];
#pragma unroll
      for (int nt = 0; nt < 4; nt++) {
        int col = n0 + wn * 64 + nt * 16 + lr;
        int b_ = col >> 12, s = col & 4095;
        y[((size_t)(b_ * Cc + c) << 12) + s] = acc[mt][nt][rg] + bc;
      }
    }
}

extern "C" void kernel_launch(void* const* d_in, const int* in_sizes, int n_in,
                              void* d_out, int out_size, void* d_ws, size_t ws_size,
                              hipStream_t stream) {
  const float* x = (const float*)d_in[0];
  const float* w_qkv = (const float*)d_in[1];
  const float* b_qkv = (const float*)d_in[2];
  const float* w_o = (const float*)d_in[3];
  const float* b_o = (const float*)d_in[4];
  float* y = (float*)d_out;
  u16* ws = (u16*)d_ws;
  u16* xt = ws;                        // [0, E) — reused as ao after k_qkv
  u16* q = ws + (size_t)ELEMS;         // [E, 2E)
  u16* k = ws + (size_t)2 * ELEMS;     // [2E, 3E)
  u16* vt = ws + (size_t)3 * ELEMS;    // [3E, 4E)
  u16* ao = xt;
  u16* wqb = ws + (size_t)4 * ELEMS;   // 196608
  u16* wob = wqb + 196608;             // 65536
  const size_t Wu16 = (size_t)4 * ELEMS + 262144;
  // tail region: v (plain V, 8.4 MB) aliases Opart (v dead before k_attn writes Opart)
  float* Opart = (float*)(ws + Wu16);
  u16* v = (u16*)Opart;
  const size_t base = Wu16 * 2;
  auto need = [&](int n) { return base + (size_t)n * ELEMS * 4 + (size_t)n * 16 * Ss * 4; };
  const int nsplit = (ws_size >= need(4)) ? 4 : (ws_size >= need(2)) ? 2 : 1;
  float* lpart = Opart + (size_t)nsplit * ELEMS;

  k_convw<<<768, 256, 0, stream>>>(w_qkv, w_o, wqb, wob);
  k_transpose<<<dim3(64, 4, 4), 256, 0, stream>>>(x, xt);
  k_qkv<<<dim3(128, 6), 256, 0, stream>>>(xt, wqb, b_qkv, q, k, v);
  k_vt<<<dim3(64, 16), 256, 0, stream>>>(v, vt);
  k_attn<<<dim3(16, 16, nsplit), 256, 0, stream>>>(q, k, vt, ao, Opart, lpart, nsplit);
  if (nsplit > 1) k_comb<<<ELEMS / 1024, 256, 0, stream>>>(Opart, lpart, ao, nsplit);
  k_oproj<<<dim3(2, 128), 256, 0, stream>>>(wob, ao, b_o, y);
}

// Round 9
// 184.670 us; speedup vs baseline: 1.0737x; 1.0737x over previous
//
#include <hip/hip_runtime.h>
#include <stdint.h>

#define DI __device__ __forceinline__

typedef __attribute__((ext_vector_type(8))) __bf16 bf16x8;
typedef __attribute__((ext_vector_type(8))) unsigned short u16x8;
typedef __attribute__((ext_vector_type(4))) float f32x4;
typedef __attribute__((ext_vector_type(4))) uint32_t u32x4;
typedef unsigned short u16;

constexpr int Bb = 4, Cc = 256, Ss = 4096, HD = 64;
constexpr int ELEMS = Bb * Cc * Ss;  // 4194304

DI u16 f2bf(float f) {
  union { float f; unsigned u; } x; x.f = f;
  return (u16)((x.u + 0x7FFFu + ((x.u >> 16) & 1u)) >> 16);
}
DI uint32_t pack2bf_trunc(float a, float b) {  // low16=bf(a), high16=bf(b), truncating
  union { float f; uint32_t u; } xa, xb;
  xa.f = a; xb.f = b;
  return __builtin_amdgcn_perm(xb.u, xa.u, 0x07060302u);
}
DI bf16x8 ldfrag(const u16* p) { return __builtin_bit_cast(bf16x8, *(const u16x8*)p); }

// ---------------- fp32 -> bf16 convert, both weight matrices in one launch ----------------
__global__ __launch_bounds__(256) void k_convw(const float* __restrict__ w1, const float* __restrict__ w2,
                                               u16* __restrict__ d1, u16* __restrict__ d2) {
  int i = blockIdx.x * 256 + threadIdx.x;
  if (i < 196608) d1[i] = f2bf(w1[i]);
  if (i < 65536) d2[i] = f2bf(w2[i]);
}

// ---------------- kernel 0: x (B,C,S) fp32 -> xt (B,S,C) bf16 ----------------
__global__ __launch_bounds__(256) void k_transpose(const float* __restrict__ x, u16* __restrict__ xt) {
  __shared__ u16 T[64][72];
  const int st = blockIdx.x, ct = blockIdx.y, b = blockIdx.z;
  const int tid = threadIdx.x;
#pragma unroll
  for (int e = 0; e < 2; e++) {
    int ss = tid + e * 256;
    int r = ss >> 3, seg = ss & 7;
    size_t base = ((size_t)(b * Cc + ct * 64 + r) << 12) + st * 64 + seg * 8;
    u16x8 t;
#pragma unroll
    for (int j = 0; j < 8; j++) t[j] = f2bf(x[base + j]);
    *(u16x8*)&T[r][seg * 8] = t;
  }
  __syncthreads();
#pragma unroll
  for (int e = 0; e < 2; e++) {
    int ss = tid + e * 256;
    int sr = ss >> 3, cseg = ss & 7;
    u16x8 o;
#pragma unroll
    for (int j = 0; j < 8; j++) o[j] = T[cseg * 8 + j][sr];
    *(u16x8*)(xt + ((size_t)(b * Ss + st * 64 + sr) << 8) + ct * 64 + cseg * 8) = o;
  }
}

// ---- shared GEMM staging: rows [r0,r0+128) x cols [k0,k0+32), pitch-40 LDS ----
DI void stage_tile(const u16* __restrict__ src, int pitch, int r0, int k0, u16 (*dst)[40], int tid) {
#pragma unroll
  for (int e = 0; e < 2; e++) {
    int c = tid + e * 256;
    int row = c >> 2, seg = c & 3;
    u16x8 t = *(const u16x8*)(src + (size_t)(r0 + row) * pitch + k0 + seg * 8);
    *(u16x8*)&dst[row][seg * 8] = t;
  }
}

// ---------------- kernel 1: qkv GEMM.  q:[bh][s][64]*(0.125*log2e)  k,v:[bh][s][64] ----------------
__global__ __launch_bounds__(256) void k_qkv(const u16* __restrict__ xt, const u16* __restrict__ w,
                                             const float* __restrict__ bias,
                                             u16* __restrict__ q, u16* __restrict__ kk_, u16* __restrict__ vv_) {
  __shared__ u16 As[128][40], Bs[128][40];
  const int tid = threadIdx.x;
  const int wv = tid >> 6, lane = tid & 63;
  const int wm = wv >> 1, wn = wv & 1;
  const int lr = lane & 15, quad = lane >> 4;
  const int r0 = blockIdx.x * 128;
  const int j0 = blockIdx.y * 128;
  f32x4 acc[4][4] = {};
  for (int k0 = 0; k0 < 256; k0 += 32) {
    __syncthreads();
    stage_tile(xt, 256, r0, k0, As, tid);
    stage_tile(w, 256, j0, k0, Bs, tid);
    __syncthreads();
    bf16x8 a[4], b[4];
#pragma unroll
    for (int mt = 0; mt < 4; mt++) a[mt] = ldfrag(&As[wm * 64 + mt * 16 + lr][quad * 8]);
#pragma unroll
    for (int nt = 0; nt < 4; nt++) b[nt] = ldfrag(&Bs[wn * 64 + nt * 16 + lr][quad * 8]);
#pragma unroll
    for (int mt = 0; mt < 4; mt++)
#pragma unroll
      for (int nt = 0; nt < 4; nt++)
        acc[mt][nt] = __builtin_amdgcn_mfma_f32_16x16x32_bf16(a[mt], b[nt], acc[mt][nt], 0, 0, 0);
  }
#pragma unroll
  for (int nt = 0; nt < 4; nt++) {
    int j = j0 + wn * 64 + nt * 16 + lr;
    float bj = bias[j];
    int part = j >> 8, cc = j & 255, head = cc >> 6, d = cc & 63;
    u16* outp = (part == 0) ? q : (part == 1) ? kk_ : vv_;
    float sc = (part == 0) ? 0.18033688f : 1.0f;  // 0.125*log2(e), exp2-domain scores
#pragma unroll
    for (int mt = 0; mt < 4; mt++)
#pragma unroll
      for (int rg = 0; rg < 4; rg++) {
        int row = r0 + wm * 64 + mt * 16 + quad * 4 + rg;
        int b_ = row >> 12, s = row & 4095;
        outp[((size_t)((b_ * 4 + head) * Ss + s) << 6) + d] = f2bf((acc[mt][nt][rg] + bj) * sc);
      }
  }
}

// ---------------- v [bh][s][64] -> vt [bh][d][chunk*64 + slot] (key-permuted transpose) ----------------
__global__ __launch_bounds__(256) void k_vt(const u16* __restrict__ v, u16* __restrict__ vt) {
  __shared__ u16 T[64][72];
  const int chunk = blockIdx.x, bh = blockIdx.y;
  const int tid = threadIdx.x;
#pragma unroll
  for (int e = 0; e < 2; e++) {
    int row = (tid >> 3) + e * 32, seg = tid & 7;
    *(u16x8*)&T[row][seg * 8] =
        *(const u16x8*)(v + ((size_t)(bh * Ss + chunk * 64 + row) << 6) + seg * 8);
  }
  __syncthreads();
#pragma unroll
  for (int e = 0; e < 2; e++) {
    int d = (tid >> 3) + e * 32, seg = tid & 7;
    u16x8 o;
#pragma unroll
    for (int j = 0; j < 8; j++) {
      int slot = seg * 8 + j;
      int t = (((slot >> 5) & 1) << 1) | ((slot >> 2) & 1);
      int w6 = t * 16 + (((slot >> 3) & 3) << 2) + (slot & 3);
      o[j] = T[w6][d];
    }
    *(u16x8*)(vt + ((size_t)(bh * 64 + d) << 12) + chunk * 64 + seg * 8) = o;
  }
}

// ---------------- kernel 2: flash attention, S^T form, exp2 no-max softmax ----------------
// 64 q/wave, 256 q-rows/block, double-buffered staging with early stores, l via ones-MFMA.
__global__ __launch_bounds__(256, 2) void k_attn(const u16* __restrict__ Q, const u16* __restrict__ K,
                                                 const u16* __restrict__ VT, u16* __restrict__ AO,
                                                 float* __restrict__ Opart, float* __restrict__ lpart,
                                                 int nsplit) {
  __shared__ u16 Kl[2][64][72];
  __shared__ u16 Vl[2][64][72];
  const int tid = threadIdx.x;
  const int wv = tid >> 6, lane = tid & 63;
  const int lr = lane & 15, quad = lane >> 4;
  const int bh = blockIdx.y;
  const int b_ = bh >> 2, head = bh & 3;
  const int qbase = blockIdx.x * 256 + wv * 64;
  const int sp = blockIdx.z;
  const int nchunk = 64 / nsplit, kcg0 = sp * nchunk;
  const u16* Qh = Q + (size_t)bh * Ss * HD;
  const u16* Kh = K + (size_t)bh * Ss * HD;
  const u16* Vh = VT + (size_t)bh * HD * Ss;  // [d][perm(s)]

  bf16x8 qb[4][2];
#pragma unroll
  for (int nt = 0; nt < 4; nt++)
#pragma unroll
    for (int ks = 0; ks < 2; ks++)
      qb[nt][ks] = ldfrag(Qh + (size_t)(qbase + nt * 16 + lr) * HD + ks * 32 + quad * 8);

  // constant all-ones B-frag for row-sum MFMA (l computation)
  u16x8 ov;
#pragma unroll
  for (int j = 0; j < 8; j++) ov[j] = 0x3F80;
  const bf16x8 ones = __builtin_bit_cast(bf16x8, ov);

  f32x4 O[4][4] = {};
  f32x4 lacc[4] = {};

  u16x8 pf[4];
  const int srow = tid >> 3, sseg = tid & 7;
  auto load_chunk = [&](int kc) {
#pragma unroll
    for (int e = 0; e < 2; e++) {
      pf[e] = *(const u16x8*)(Kh + ((size_t)((kcg0 + kc) * 64 + srow + e * 32) << 6) + sseg * 8);
      pf[2 + e] = *(const u16x8*)(Vh + ((size_t)(srow + e * 32) << 12) + (kcg0 + kc) * 64 + sseg * 8);
    }
  };
  auto store_chunk = [&](int buf) {
#pragma unroll
    for (int e = 0; e < 2; e++) {
      *(u16x8*)&Kl[buf][srow + e * 32][sseg * 8] = pf[e];
      *(u16x8*)&Vl[buf][srow + e * 32][sseg * 8] = pf[2 + e];
    }
  };

  load_chunk(0);
  store_chunk(0);
  if (nchunk > 1) load_chunk(1);
  __syncthreads();

  for (int kc = 0; kc < nchunk; kc++) {
    const int cur = kc & 1;
    // early: store chunk kc+1 into other buffer (its reads finished at end of iter kc-1),
    // and issue global loads for kc+2 — both overlap this iter's MFMA/exp work.
    if (kc + 1 < nchunk) {
      store_chunk(cur ^ 1);
      if (kc + 2 < nchunk) load_chunk(kc + 2);
    }

    f32x4 St[4][4] = {};
#pragma unroll
    for (int ks = 0; ks < 2; ks++) {
      bf16x8 ka[4];
#pragma unroll
      for (int kt = 0; kt < 4; kt++) ka[kt] = ldfrag(&Kl[cur][kt * 16 + lr][ks * 32 + quad * 8]);
#pragma unroll
      for (int kt = 0; kt < 4; kt++)
#pragma unroll
        for (int nt = 0; nt < 4; nt++)
          St[kt][nt] = __builtin_amdgcn_mfma_f32_16x16x32_bf16(ka[kt], qb[nt][ks], St[kt][nt], 0, 0, 0);
    }

    uint32_t pk[4][4][2];
#pragma unroll
    for (int kt = 0; kt < 4; kt++)
#pragma unroll
      for (int nt = 0; nt < 4; nt++) {
        float p0 = __builtin_amdgcn_exp2f(St[kt][nt][0]);
        float p1 = __builtin_amdgcn_exp2f(St[kt][nt][1]);
        float p2 = __builtin_amdgcn_exp2f(St[kt][nt][2]);
        float p3 = __builtin_amdgcn_exp2f(St[kt][nt][3]);
        pk[kt][nt][0] = pack2bf_trunc(p0, p1);
        pk[kt][nt][1] = pack2bf_trunc(p2, p3);
      }

#pragma unroll
    for (int ks = 0; ks < 2; ks++) {
      bf16x8 pa[4];
#pragma unroll
      for (int mt = 0; mt < 4; mt++) {
        u32x4 t = {pk[2 * ks][mt][0], pk[2 * ks][mt][1], pk[2 * ks + 1][mt][0], pk[2 * ks + 1][mt][1]};
        pa[mt] = __builtin_bit_cast(bf16x8, t);
      }
#pragma unroll
      for (int dt = 0; dt < 4; dt++) {
        bf16x8 vb = ldfrag(&Vl[cur][dt * 16 + lr][ks * 32 + quad * 8]);
#pragma unroll
        for (int mt = 0; mt < 4; mt++)
          O[mt][dt] = __builtin_amdgcn_mfma_f32_16x16x32_bf16(pa[mt], vb, O[mt][dt], 0, 0, 0);
      }
      // l[q] += sum_k P[q][k]  (D rows = q = A m-index; every lane holds its q's l in reg rg)
#pragma unroll
      for (int mt = 0; mt < 4; mt++)
        lacc[mt] = __builtin_amdgcn_mfma_f32_16x16x32_bf16(pa[mt], ones, lacc[mt], 0, 0, 0);
    }

    __syncthreads();
  }

  if (nsplit == 1) {
#pragma unroll
    for (int mt = 0; mt < 4; mt++)
#pragma unroll
      for (int rg = 0; rg < 4; rg++) {
        float inv = 1.0f / lacc[mt][rg];
        int s = qbase + mt * 16 + quad * 4 + rg;
#pragma unroll
        for (int dt = 0; dt < 4; dt++)
          AO[((size_t)(b_ * Ss + s) << 8) + head * 64 + dt * 16 + lr] = f2bf(O[mt][dt][rg] * inv);
      }
  } else {
    float* Op = Opart + (size_t)sp * ELEMS;
    float* lp = lpart + (size_t)sp * (16 * Ss) + bh * Ss;
    if (lr == 0) {
#pragma unroll
      for (int mt = 0; mt < 4; mt++)
#pragma unroll
        for (int rg = 0; rg < 4; rg++) lp[qbase + mt * 16 + quad * 4 + rg] = lacc[mt][rg];
    }
#pragma unroll
    for (int mt = 0; mt < 4; mt++)
#pragma unroll
      for (int rg = 0; rg < 4; rg++) {
        int s = qbase + mt * 16 + quad * 4 + rg;
#pragma unroll
        for (int dt = 0; dt < 4; dt++)
          Op[((size_t)(b_ * Ss + s) << 8) + head * 64 + dt * 16 + lr] = O[mt][dt][rg];
      }
  }
}

// ---------------- kernel 3 (fused combine + oproj): y^T = w_o * ((ΣO)/(Σl))^T + b_o ----------------
// 512 threads, 256(c) x 128(n) tile, grid 128. B-staging combines fp32 partials -> bf16.
__global__ __launch_bounds__(512) void k_oproj(const u16* __restrict__ wo, const u16* __restrict__ ao,
                                               const float* __restrict__ Opart, const float* __restrict__ lpart,
                                               const float* __restrict__ bo, float* __restrict__ y, int nsplit) {
  __shared__ u16 As[256][40], Bs[128][40];
  const int tid = threadIdx.x;
  const int wv = tid >> 6, lane = tid & 63;
  const int wm = wv >> 1, wn = wv & 1;  // wm 0..3 (64c each), wn 0..1 (64n each)
  const int lr = lane & 15, quad = lane >> 4;
  const int n0 = blockIdx.x * 128;
  f32x4 acc[4][4] = {};
  for (int k0 = 0; k0 < 256; k0 += 32) {
    __syncthreads();
#pragma unroll
    for (int e = 0; e < 2; e++) {  // A: 256 rows x 32 cols
      int c = tid + e * 512;
      int row = c >> 2, seg = c & 3;
      *(u16x8*)&As[row][seg * 8] = *(const u16x8*)(wo + row * 256 + k0 + seg * 8);
    }
    {  // B: 128 n-rows x 32 c-cols, combined from partials
      int c = tid;
      int row = c >> 2, seg = c & 3;
      int bs = n0 + row, cc = k0 + seg * 8;
      u16x8 t;
      if (nsplit == 1) {
        t = *(const u16x8*)(ao + ((size_t)bs << 8) + cc);
      } else {
        int b = bs >> 12, s = bs & 4095, head = cc >> 6;
        int li = (b * 4 + head) * Ss + s;
        f32x4 o0 = {}, o1 = {};
        float l = 0.f;
        for (int j = 0; j < nsplit; j++) {
          const float* Op = Opart + (size_t)j * ELEMS + ((size_t)bs << 8) + cc;
          f32x4 a0 = *(const f32x4*)Op, a1 = *(const f32x4*)(Op + 4);
#pragma unroll
          for (int i = 0; i < 4; i++) { o0[i] += a0[i]; o1[i] += a1[i]; }
          l += lpart[(size_t)j * 16 * Ss + li];
        }
        float inv = 1.0f / l;
#pragma unroll
        for (int i = 0; i < 4; i++) { t[i] = f2bf(o0[i] * inv); t[4 + i] = f2bf(o1[i] * inv); }
      }
      *(u16x8*)&Bs[row][seg * 8] = t;
    }
    __syncthreads();
    bf16x8 a[4], b[4];
#pragma unroll
    for (int mt = 0; mt < 4; mt++) a[mt] = ldfrag(&As[wm * 64 + mt * 16 + lr][quad * 8]);
#pragma unroll
    for (int nt = 0; nt < 4; nt++) b[nt] = ldfrag(&Bs[wn * 64 + nt * 16 + lr][quad * 8]);
#pragma unroll
    for (int mt = 0; mt < 4; mt++)
#pragma unroll
      for (int nt = 0; nt < 4; nt++)
        acc[mt][nt] = __builtin_amdgcn_mfma_f32_16x16x32_bf16(a[mt], b[nt], acc[mt][nt], 0, 0, 0);
  }
#pragma unroll
  for (int mt = 0; mt < 4; mt++)
#pragma unroll
    for (int rg = 0; rg < 4; rg++) {
      int c = wm * 64 + mt * 16 + quad * 4 + rg;
      float bc = bo[c];
#pragma unroll
      for (int nt = 0; nt < 4; nt++) {
        int col = n0 + wn * 64 + nt * 16 + lr;
        int b_ = col >> 12, s = col & 4095;
        y[((size_t)(b_ * Cc + c) << 12) + s] = acc[mt][nt][rg] + bc;
      }
    }
}

extern "C" void kernel_launch(void* const* d_in, const int* in_sizes, int n_in,
                              void* d_out, int out_size, void* d_ws, size_t ws_size,
                              hipStream_t stream) {
  const float* x = (const float*)d_in[0];
  const float* w_qkv = (const float*)d_in[1];
  const float* b_qkv = (const float*)d_in[2];
  const float* w_o = (const float*)d_in[3];
  const float* b_o = (const float*)d_in[4];
  float* y = (float*)d_out;
  u16* ws = (u16*)d_ws;
  u16* xt = ws;                        // [0, E) — reused as ao (nsplit==1 fallback)
  u16* q = ws + (size_t)ELEMS;
  u16* k = ws + (size_t)2 * ELEMS;
  u16* vt = ws + (size_t)3 * ELEMS;
  u16* ao = xt;
  u16* wqb = ws + (size_t)4 * ELEMS;   // 196608
  u16* wob = wqb + 196608;             // 65536
  const size_t Wu16 = (size_t)4 * ELEMS + 262144;
  float* Opart = (float*)(ws + Wu16);
  u16* v = (u16*)Opart;  // plain V aliases Opart (dead before k_attn writes)
  const size_t base = Wu16 * 2;
  auto need = [&](int n) { return base + (size_t)n * ELEMS * 4 + (size_t)n * 16 * Ss * 4; };
  const int nsplit = (ws_size >= need(2)) ? 2 : 1;
  float* lpart = Opart + (size_t)nsplit * ELEMS;

  k_convw<<<768, 256, 0, stream>>>(w_qkv, w_o, wqb, wob);
  k_transpose<<<dim3(64, 4, 4), 256, 0, stream>>>(x, xt);
  k_qkv<<<dim3(128, 6), 256, 0, stream>>>(xt, wqb, b_qkv, q, k, v);
  k_vt<<<dim3(64, 16), 256, 0, stream>>>(v, vt);
  k_attn<<<dim3(16, 16, nsplit), 256, 0, stream>>>(q, k, vt, ao, Opart, lpart, nsplit);
  k_oproj<<<128, 512, 0, stream>>>(wob, ao, Opart, lpart, b_o, y, nsplit);
}

// Round 10
// 177.098 us; speedup vs baseline: 1.1196x; 1.0428x over previous
//
#include <hip/hip_runtime.h>
#include <stdint.h>

#define DI __device__ __forceinline__

typedef __attribute__((ext_vector_type(8))) __bf16 bf16x8;
typedef __attribute__((ext_vector_type(8))) unsigned short u16x8;
typedef __attribute__((ext_vector_type(4))) float f32x4;
typedef __attribute__((ext_vector_type(4))) uint32_t u32x4;
typedef unsigned short u16;

constexpr int Bb = 4, Cc = 256, Ss = 4096, HD = 64;
constexpr int ELEMS = Bb * Cc * Ss;  // 4194304

DI float bf2f(u16 h) { union { unsigned u; float f; } x; x.u = ((unsigned)h) << 16; return x.f; }
DI u16 f2bf(float f) {
  union { float f; unsigned u; } x; x.f = f;
  return (u16)((x.u + 0x7FFFu + ((x.u >> 16) & 1u)) >> 16);
}
DI uint32_t pack2bf_trunc(float a, float b) {  // low16=bf(a), high16=bf(b), truncating
  union { float f; uint32_t u; } xa, xb;
  xa.f = a; xb.f = b;
  return __builtin_amdgcn_perm(xb.u, xa.u, 0x07060302u);
}
DI bf16x8 ldfrag(const u16* p) { return __builtin_bit_cast(bf16x8, *(const u16x8*)p); }

// ---------------- kernel 0: x (B,C,S) fp32 -> xt (B,S,C) bf16; + weight conversion fused ----------------
// LDS uses XOR column-block swizzle: element (r,c) lives at T[r][((c>>3)^((r>>3)&7))*8 + (c&7)].
// Write: vector u16x8, ~2-way banks. Read: scalar, all-32-banks distinct (was 16-way conflicted).
__global__ __launch_bounds__(256) void k_transpose(const float* __restrict__ x, u16* __restrict__ xt,
                                                   const float* __restrict__ wq, const float* __restrict__ wo,
                                                   u16* __restrict__ wqb, u16* __restrict__ wob) {
  __shared__ u16 T[64][72];
  const int st = blockIdx.x, ct = blockIdx.y, b = blockIdx.z;
  const int tid = threadIdx.x;
  // fused weight conversion: 1024 blocks x 256 threads == 262144 == 196608 + 65536
  {
    int flat = blockIdx.x + 64 * blockIdx.y + 256 * blockIdx.z;
    int widx = flat * 256 + tid;
    if (widx < 196608) wqb[widx] = f2bf(wq[widx]);
    else wob[widx - 196608] = f2bf(wo[widx - 196608]);
  }
#pragma unroll
  for (int e = 0; e < 2; e++) {
    int ss = tid + e * 256;
    int r = ss >> 3, seg = ss & 7;
    size_t base = ((size_t)(b * Cc + ct * 64 + r) << 12) + st * 64 + seg * 8;
    u16x8 t;
#pragma unroll
    for (int j = 0; j < 8; j++) t[j] = f2bf(x[base + j]);
    *(u16x8*)&T[r][(seg ^ ((r >> 3) & 7)) * 8] = t;
  }
  __syncthreads();
#pragma unroll
  for (int e = 0; e < 2; e++) {
    int ss = tid + e * 256;
    int sr = ss >> 3, cseg = ss & 7;
    u16x8 o;
#pragma unroll
    for (int j = 0; j < 8; j++) {
      int row = cseg * 8 + j;
      o[j] = T[row][(((sr >> 3) ^ cseg) * 8) + (sr & 7)];
    }
    *(u16x8*)(xt + ((size_t)(b * Ss + st * 64 + sr) << 8) + ct * 64 + cseg * 8) = o;
  }
}

// ---- shared GEMM staging: rows [r0,r0+128) x cols [k0,k0+32), pitch-40 LDS ----
DI void stage_tile(const u16* __restrict__ src, int pitch, int r0, int k0, u16 (*dst)[40], int tid) {
#pragma unroll
  for (int e = 0; e < 2; e++) {
    int c = tid + e * 256;
    int row = c >> 2, seg = c & 3;
    u16x8 t = *(const u16x8*)(src + (size_t)(r0 + row) * pitch + k0 + seg * 8);
    *(u16x8*)&dst[row][seg * 8] = t;
  }
}

// ---------------- kernel 1: qkv GEMM.  q:[bh][s][64]*(0.125*log2e)  k,v:[bh][s][64] ----------------
__global__ __launch_bounds__(256) void k_qkv(const u16* __restrict__ xt, const u16* __restrict__ w,
                                             const float* __restrict__ bias,
                                             u16* __restrict__ q, u16* __restrict__ kk_, u16* __restrict__ vv_) {
  __shared__ u16 As[128][40], Bs[128][40];
  const int tid = threadIdx.x;
  const int wv = tid >> 6, lane = tid & 63;
  const int wm = wv >> 1, wn = wv & 1;
  const int lr = lane & 15, quad = lane >> 4;
  const int r0 = blockIdx.x * 128;
  const int j0 = blockIdx.y * 128;
  f32x4 acc[4][4] = {};
  for (int k0 = 0; k0 < 256; k0 += 32) {
    __syncthreads();
    stage_tile(xt, 256, r0, k0, As, tid);
    stage_tile(w, 256, j0, k0, Bs, tid);
    __syncthreads();
    bf16x8 a[4], b[4];
#pragma unroll
    for (int mt = 0; mt < 4; mt++) a[mt] = ldfrag(&As[wm * 64 + mt * 16 + lr][quad * 8]);
#pragma unroll
    for (int nt = 0; nt < 4; nt++) b[nt] = ldfrag(&Bs[wn * 64 + nt * 16 + lr][quad * 8]);
#pragma unroll
    for (int mt = 0; mt < 4; mt++)
#pragma unroll
      for (int nt = 0; nt < 4; nt++)
        acc[mt][nt] = __builtin_amdgcn_mfma_f32_16x16x32_bf16(a[mt], b[nt], acc[mt][nt], 0, 0, 0);
  }
#pragma unroll
  for (int nt = 0; nt < 4; nt++) {
    int j = j0 + wn * 64 + nt * 16 + lr;
    float bj = bias[j];
    int part = j >> 8, cc = j & 255, head = cc >> 6, d = cc & 63;
    u16* outp = (part == 0) ? q : (part == 1) ? kk_ : vv_;
    float sc = (part == 0) ? 0.18033688f : 1.0f;  // 0.125*log2(e), exp2-domain scores
#pragma unroll
    for (int mt = 0; mt < 4; mt++)
#pragma unroll
      for (int rg = 0; rg < 4; rg++) {
        int row = r0 + wm * 64 + mt * 16 + quad * 4 + rg;
        int b_ = row >> 12, s = row & 4095;
        outp[((size_t)((b_ * 4 + head) * Ss + s) << 6) + d] = f2bf((acc[mt][nt][rg] + bj) * sc);
      }
  }
}

// ---------------- v [bh][s][64] -> vt [bh][d][chunk*64 + slot] (key-permuted transpose) ----------------
// Same XOR swizzle on the LDS tile to break read conflicts.
__global__ __launch_bounds__(256) void k_vt(const u16* __restrict__ v, u16* __restrict__ vt) {
  __shared__ u16 T[64][72];
  const int chunk = blockIdx.x, bh = blockIdx.y;
  const int tid = threadIdx.x;
#pragma unroll
  for (int e = 0; e < 2; e++) {
    int row = (tid >> 3) + e * 32, seg = tid & 7;
    *(u16x8*)&T[row][(seg ^ ((row >> 3) & 7)) * 8] =
        *(const u16x8*)(v + ((size_t)(bh * Ss + chunk * 64 + row) << 6) + seg * 8);
  }
  __syncthreads();
#pragma unroll
  for (int e = 0; e < 2; e++) {
    int d = (tid >> 3) + e * 32, seg = tid & 7;
    u16x8 o;
#pragma unroll
    for (int j = 0; j < 8; j++) {
      int slot = seg * 8 + j;
      int t = (((slot >> 5) & 1) << 1) | ((slot >> 2) & 1);
      int w6 = t * 16 + (((slot >> 3) & 3) << 2) + (slot & 3);
      o[j] = T[w6][(((d >> 3) ^ ((w6 >> 3) & 7)) * 8) + (d & 7)];
    }
    *(u16x8*)(vt + ((size_t)(bh * 64 + d) << 12) + chunk * 64 + seg * 8) = o;
  }
}

// ---------------- kernel 2: flash attention, S^T form, exp2 no-max softmax ----------------
// 64 q/wave, 256 q-rows/block, double-buffered staging with early stores, l via ones-MFMA.
// K-split: each split writes NORMALIZED bf16 partials + l; combine is an l-weighted average.
__global__ __launch_bounds__(256, 2) void k_attn(const u16* __restrict__ Q, const u16* __restrict__ K,
                                                 const u16* __restrict__ VT, u16* __restrict__ AO,
                                                 u16* __restrict__ AOP, float* __restrict__ lpart,
                                                 int nsplit) {
  __shared__ u16 Kl[2][64][72];
  __shared__ u16 Vl[2][64][72];
  const int tid = threadIdx.x;
  const int wv = tid >> 6, lane = tid & 63;
  const int lr = lane & 15, quad = lane >> 4;
  const int bh = blockIdx.y;
  const int b_ = bh >> 2, head = bh & 3;
  const int qbase = blockIdx.x * 256 + wv * 64;
  const int sp = blockIdx.z;
  const int nchunk = 64 / nsplit, kcg0 = sp * nchunk;
  const u16* Qh = Q + (size_t)bh * Ss * HD;
  const u16* Kh = K + (size_t)bh * Ss * HD;
  const u16* Vh = VT + (size_t)bh * HD * Ss;  // [d][perm(s)]

  bf16x8 qb[4][2];
#pragma unroll
  for (int nt = 0; nt < 4; nt++)
#pragma unroll
    for (int ks = 0; ks < 2; ks++)
      qb[nt][ks] = ldfrag(Qh + (size_t)(qbase + nt * 16 + lr) * HD + ks * 32 + quad * 8);

  u16x8 ov;
#pragma unroll
  for (int j = 0; j < 8; j++) ov[j] = 0x3F80;
  const bf16x8 ones = __builtin_bit_cast(bf16x8, ov);

  f32x4 O[4][4] = {};
  f32x4 lacc[4] = {};

  u16x8 pf[4];
  const int srow = tid >> 3, sseg = tid & 7;
  auto load_chunk = [&](int kc) {
#pragma unroll
    for (int e = 0; e < 2; e++) {
      pf[e] = *(const u16x8*)(Kh + ((size_t)((kcg0 + kc) * 64 + srow + e * 32) << 6) + sseg * 8);
      pf[2 + e] = *(const u16x8*)(Vh + ((size_t)(srow + e * 32) << 12) + (kcg0 + kc) * 64 + sseg * 8);
    }
  };
  auto store_chunk = [&](int buf) {
#pragma unroll
    for (int e = 0; e < 2; e++) {
      *(u16x8*)&Kl[buf][srow + e * 32][sseg * 8] = pf[e];
      *(u16x8*)&Vl[buf][srow + e * 32][sseg * 8] = pf[2 + e];
    }
  };

  load_chunk(0);
  store_chunk(0);
  if (nchunk > 1) load_chunk(1);
  __syncthreads();

  for (int kc = 0; kc < nchunk; kc++) {
    const int cur = kc & 1;
    if (kc + 1 < nchunk) {
      store_chunk(cur ^ 1);
      if (kc + 2 < nchunk) load_chunk(kc + 2);
    }

    f32x4 St[4][4] = {};
#pragma unroll
    for (int ks = 0; ks < 2; ks++) {
      bf16x8 ka[4];
#pragma unroll
      for (int kt = 0; kt < 4; kt++) ka[kt] = ldfrag(&Kl[cur][kt * 16 + lr][ks * 32 + quad * 8]);
#pragma unroll
      for (int kt = 0; kt < 4; kt++)
#pragma unroll
        for (int nt = 0; nt < 4; nt++)
          St[kt][nt] = __builtin_amdgcn_mfma_f32_16x16x32_bf16(ka[kt], qb[nt][ks], St[kt][nt], 0, 0, 0);
    }

    uint32_t pk[4][4][2];
#pragma unroll
    for (int kt = 0; kt < 4; kt++)
#pragma unroll
      for (int nt = 0; nt < 4; nt++) {
        float p0 = __builtin_amdgcn_exp2f(St[kt][nt][0]);
        float p1 = __builtin_amdgcn_exp2f(St[kt][nt][1]);
        float p2 = __builtin_amdgcn_exp2f(St[kt][nt][2]);
        float p3 = __builtin_amdgcn_exp2f(St[kt][nt][3]);
        pk[kt][nt][0] = pack2bf_trunc(p0, p1);
        pk[kt][nt][1] = pack2bf_trunc(p2, p3);
      }

#pragma unroll
    for (int ks = 0; ks < 2; ks++) {
      bf16x8 pa[4];
#pragma unroll
      for (int mt = 0; mt < 4; mt++) {
        u32x4 t = {pk[2 * ks][mt][0], pk[2 * ks][mt][1], pk[2 * ks + 1][mt][0], pk[2 * ks + 1][mt][1]};
        pa[mt] = __builtin_bit_cast(bf16x8, t);
      }
#pragma unroll
      for (int dt = 0; dt < 4; dt++) {
        bf16x8 vb = ldfrag(&Vl[cur][dt * 16 + lr][ks * 32 + quad * 8]);
#pragma unroll
        for (int mt = 0; mt < 4; mt++)
          O[mt][dt] = __builtin_amdgcn_mfma_f32_16x16x32_bf16(pa[mt], vb, O[mt][dt], 0, 0, 0);
      }
#pragma unroll
      for (int mt = 0; mt < 4; mt++)
        lacc[mt] = __builtin_amdgcn_mfma_f32_16x16x32_bf16(pa[mt], ones, lacc[mt], 0, 0, 0);
    }

    __syncthreads();
  }

  // epilogue: normalize by this split's l, write bf16 (AO if nsplit==1, else partial slot sp)
  u16* dst = (nsplit == 1) ? AO : (AOP + (size_t)sp * ELEMS);
  if (nsplit > 1 && lr == 0) {
    float* lp = lpart + (size_t)sp * (16 * Ss) + bh * Ss;
#pragma unroll
    for (int mt = 0; mt < 4; mt++)
#pragma unroll
      for (int rg = 0; rg < 4; rg++) lp[qbase + mt * 16 + quad * 4 + rg] = lacc[mt][rg];
  }
#pragma unroll
  for (int mt = 0; mt < 4; mt++)
#pragma unroll
    for (int rg = 0; rg < 4; rg++) {
      float inv = 1.0f / lacc[mt][rg];
      int s = qbase + mt * 16 + quad * 4 + rg;
#pragma unroll
      for (int dt = 0; dt < 4; dt++)
        dst[((size_t)(b_ * Ss + s) << 8) + head * 64 + dt * 16 + lr] = f2bf(O[mt][dt][rg] * inv);
    }
}

// ---------------- kernel 3 (fused combine + oproj): y^T = w_o * combine(aop)^T + b_o ----------------
// 512 threads, 256(c) x 128(n) tile, grid 128. B-staging does l-weighted average of bf16 partials.
__global__ __launch_bounds__(512) void k_oproj(const u16* __restrict__ wo, const u16* __restrict__ ao,
                                               const u16* __restrict__ AOP, const float* __restrict__ lpart,
                                               const float* __restrict__ bo, float* __restrict__ y, int nsplit) {
  __shared__ u16 As[256][40], Bs[128][40];
  const int tid = threadIdx.x;
  const int wv = tid >> 6, lane = tid & 63;
  const int wm = wv >> 1, wn = wv & 1;
  const int lr = lane & 15, quad = lane >> 4;
  const int n0 = blockIdx.x * 128;
  f32x4 acc[4][4] = {};
  for (int k0 = 0; k0 < 256; k0 += 32) {
    __syncthreads();
#pragma unroll
    for (int e = 0; e < 2; e++) {  // A: 256 rows x 32 cols
      int c = tid + e * 512;
      int row = c >> 2, seg = c & 3;
      *(u16x8*)&As[row][seg * 8] = *(const u16x8*)(wo + row * 256 + k0 + seg * 8);
    }
    {  // B: 128 n-rows x 32 c-cols, l-weighted combine of normalized bf16 partials
      int row = tid >> 2, seg = tid & 3;
      int bs = n0 + row, cc = k0 + seg * 8;
      u16x8 t;
      if (nsplit == 1) {
        t = *(const u16x8*)(ao + ((size_t)bs << 8) + cc);
      } else {
        int b = bs >> 12, s = bs & 4095, head = cc >> 6;
        int li = (b * 4 + head) * Ss + s;
        u16x8 a0 = *(const u16x8*)(AOP + ((size_t)bs << 8) + cc);
        u16x8 a1 = *(const u16x8*)(AOP + (size_t)ELEMS + ((size_t)bs << 8) + cc);
        float l0 = lpart[li], l1 = lpart[16 * Ss + li];
        float inv = 1.0f / (l0 + l1);
        float w0 = l0 * inv, w1 = l1 * inv;
#pragma unroll
        for (int i = 0; i < 8; i++) t[i] = f2bf(w0 * bf2f(a0[i]) + w1 * bf2f(a1[i]));
      }
      *(u16x8*)&Bs[row][seg * 8] = t;
    }
    __syncthreads();
    bf16x8 a[4], b[4];
#pragma unroll
    for (int mt = 0; mt < 4; mt++) a[mt] = ldfrag(&As[wm * 64 + mt * 16 + lr][quad * 8]);
#pragma unroll
    for (int nt = 0; nt < 4; nt++) b[nt] = ldfrag(&Bs[wn * 64 + nt * 16 + lr][quad * 8]);
#pragma unroll
    for (int mt = 0; mt < 4; mt++)
#pragma unroll
      for (int nt = 0; nt < 4; nt++)
        acc[mt][nt] = __builtin_amdgcn_mfma_f32_16x16x32_bf16(a[mt], b[nt], acc[mt][nt], 0, 0, 0);
  }
#pragma unroll
  for (int mt = 0; mt < 4; mt++)
#pragma unroll
    for (int rg = 0; rg < 4; rg++) {
      int c = wm * 64 + mt * 16 + quad * 4 + rg;
      float bc = bo[c];
#pragma unroll
      for (int nt = 0; nt < 4; nt++) {
        int col = n0 + wn * 64 + nt * 16 + lr;
        int b_ = col >> 12, s = col & 4095;
        y[((size_t)(b_ * Cc + c) << 12) + s] = acc[mt][nt][rg] + bc;
      }
    }
}

extern "C" void kernel_launch(void* const* d_in, const int* in_sizes, int n_in,
                              void* d_out, int out_size, void* d_ws, size_t ws_size,
                              hipStream_t stream) {
  const float* x = (const float*)d_in[0];
  const float* w_qkv = (const float*)d_in[1];
  const float* b_qkv = (const float*)d_in[2];
  const float* w_o = (const float*)d_in[3];
  const float* b_o = (const float*)d_in[4];
  float* y = (float*)d_out;
  u16* ws = (u16*)d_ws;
  u16* xt = ws;                        // [0, E) — reused as ao (nsplit==1 fallback)
  u16* q = ws + (size_t)ELEMS;
  u16* k = ws + (size_t)2 * ELEMS;
  u16* vt = ws + (size_t)3 * ELEMS;
  u16* ao = xt;
  u16* wqb = ws + (size_t)4 * ELEMS;   // 196608
  u16* wob = wqb + 196608;             // 65536
  const size_t Wu16 = (size_t)4 * ELEMS + 262144;
  u16* aop = ws + Wu16;                // 2*ELEMS u16 normalized partials
  u16* v = aop;                        // plain V aliases aop (dead before k_attn writes)
  float* lpart = (float*)(aop + (size_t)2 * ELEMS);
  const size_t need = (Wu16 + (size_t)2 * ELEMS) * 2 + (size_t)2 * 16 * Ss * 4;
  const int nsplit = (ws_size >= need) ? 2 : 1;

  k_transpose<<<dim3(64, 4, 4), 256, 0, stream>>>(x, xt, w_qkv, w_o, wqb, wob);
  k_qkv<<<dim3(128, 6), 256, 0, stream>>>(xt, wqb, b_qkv, q, k, v);
  k_vt<<<dim3(64, 16), 256, 0, stream>>>(v, vt);
  k_attn<<<dim3(16, 16, nsplit), 256, 0, stream>>>(q, k, vt, ao, aop, lpart, nsplit);
  k_oproj<<<128, 512, 0, stream>>>(wob, ao, aop, lpart, b_o, y, nsplit);
}